// Round 6
// baseline (253.666 us; speedup 1.0000x reference)
//
#include <hip/hip_runtime.h>
#include <stdint.h>

// x: [B=8, L=131072, C=16] f32, integer values in [0,5). K=9, pad_l=3, pad_r=4
// -> output length L-1 = 131071. Outputs (soft-argmax, density) each
// [B, Lout, C] f32, concatenated flat in d_out.
//
// R6 structure: one wave = one span of 56 outputs, 64 loaded positions
// (8-lane overlap), ALL 16 channels per lane, nibble-packed counts
// (2 channels per u32, 4 bits per value bin; window count <= 9 so no carry).
// 9-window sum = 4-step shfl_down tree; no scan, no cross-iteration carries.
// Wave loads 4KB contiguous; stores 2 x 3.5KB contiguous. 32 DS-ops / 56 pos.
constexpr int Bn   = 8;
constexpr int Ln   = 131072;
constexpr int Cn   = 16;
constexpr int Lout = Ln - 1;
constexpr int CG   = Cn / 4;                     // f4 per position
constexpr int OPW  = 56;                         // outputs per wave
constexpr int NSPAN = (Lout + OPW - 1) / OPW;    // 2341
constexpr int WPB  = 4;                          // waves per 256-block
constexpr int XBLK = (NSPAN + WPB - 1) / WPB;    // 586

typedef float f4 __attribute__((ext_vector_type(4)));

__global__ __launch_bounds__(256)
void mop_kernel(const f4* __restrict__ x, f4* __restrict__ outp) {
    f4* dens = outp + (size_t)Bn * Lout * CG;

    const int lane = threadIdx.x & 63;
    const int span = blockIdx.x * WPB + (threadIdx.x >> 6);
    const int b    = blockIdx.y;
    if (span >= NSPAN) return;

    // input position this lane covers (window support for outputs l0..l0+55)
    const int p = span * OPW - 3 + lane;

    f4 v0 = (f4)0.f, v1 = (f4)0.f, v2 = (f4)0.f, v3 = (f4)0.f;
    if (p >= 0 && p < Ln) {
        const f4* xp = x + ((size_t)b * Ln + p) * CG;
        v0 = xp[0]; v1 = xp[1]; v2 = xp[2]; v3 = xp[3];
    }

    // nibble-packed one-hot indicator: value v in 1..4 -> nibble v gets 1;
    // v==0 contributes nothing. 2 channels per u32 word.
    float vals[16] = {v0.x, v0.y, v0.z, v0.w, v1.x, v1.y, v1.z, v1.w,
                      v2.x, v2.y, v2.z, v2.w, v3.x, v3.y, v3.z, v3.w};
    uint32_t E[8];
    #pragma unroll
    for (int i = 0; i < 8; ++i) {
        int a0 = (int)vals[2 * i], a1 = (int)vals[2 * i + 1];
        uint32_t n0 = (1u << (4 * a0)) >> 4;   // v=0 underflows to 0
        uint32_t n1 = (1u << (4 * a1)) >> 4;
        E[i] = n0 | (n1 << 16);
    }

    // 9-wide forward window sum A(k) = sum E(k..k+8), valid for k <= 55.
    // Nibble adds never carry (max 9 < 16).
    uint32_t A[8];
    #pragma unroll
    for (int i = 0; i < 8; ++i) {
        uint32_t e  = E[i];
        uint32_t b1 = e  + __shfl_down(e, 1);
        uint32_t b2 = b1 + __shfl_down(b1, 2);
        uint32_t b4 = b2 + __shfl_down(b2, 4);
        A[i] = b4 + __shfl_down(e, 8);
    }

    const int l = span * OPW + lane;           // output position of lane k
    if (lane < OPW && l < Lout) {
        float o[16], dd[16];
        #pragma unroll
        for (int i = 0; i < 8; ++i) {
            #pragma unroll
            for (int h = 0; h < 2; ++h) {
                uint32_t w = h ? (A[i] >> 16) : (A[i] & 0xFFFFu);
                int c1 = w & 15, c2 = (w >> 4) & 15, c3 = (w >> 8) & 15, c4 = (w >> 12) & 15;
                int m = max(max(c1, c2), max(c3, c4));
                // tie-averaged argmax (softmax@1e10 == 1/n per max bin)
                int n = (c1 == m) + (c2 == m) + (c3 == m) + (c4 == m);
                int s = (c1 == m) + 2 * (c2 == m) + 3 * (c3 == m) + 4 * (c4 == m);
                float r = (n == 1) ? 1.0f : (n == 2) ? 0.5f : (n == 3) ? (1.0f / 3.0f) : 0.25f;
                int c = 2 * i + h;
                o[c]  = (m == 0) ? 0.0f : (float)s * r;   // m==0 -> bin 0 wins alone
                dd[c] = (m == 0) ? 1.0f : (float)m;
            }
        }
        f4* ob = outp + ((size_t)b * Lout + l) * CG;
        f4* db = dens + ((size_t)b * Lout + l) * CG;
        #pragma unroll
        for (int q = 0; q < 4; ++q) {
            f4 o4 = {o[4 * q], o[4 * q + 1], o[4 * q + 2], o[4 * q + 3]};
            __builtin_nontemporal_store(o4, &ob[q]);
        }
        #pragma unroll
        for (int q = 0; q < 4; ++q) {
            f4 d4 = {dd[4 * q], dd[4 * q + 1], dd[4 * q + 2], dd[4 * q + 3]};
            __builtin_nontemporal_store(d4, &db[q]);
        }
    }
}

extern "C" void kernel_launch(void* const* d_in, const int* in_sizes, int n_in,
                              void* d_out, int out_size, void* d_ws, size_t ws_size,
                              hipStream_t stream) {
    const f4* x = (const f4*)d_in[0];
    f4* outp = (f4*)d_out;
    dim3 grid(XBLK, Bn);
    mop_kernel<<<grid, 256, 0, stream>>>(x, outp);
}

// Round 7
// 200.080 us; speedup vs baseline: 1.2678x; 1.2678x over previous
//
#include <hip/hip_runtime.h>
#include <stdint.h>

// x: [B=8, L=131072, C=16] f32, integer values in [0,5). K=9, pad_l=3, pad_r=4
// -> output length L-1 = 131071. Outputs (soft-argmax, density) each
// [B, Lout, C] f32, concatenated flat in d_out.
//
// R7 = R6 structure (wave = 56-output span, 8-lane overlap, nibble-packed
// counts, shfl_down window tree) with PLAIN stores: the 4x 16B/lane
// stride-64B store instructions merge into full lines in L2. NT stores here
// bypassed L2 write-combine -> 1.94x WRITE_SIZE (measured R6: 255MB vs 131MB).
constexpr int Bn   = 8;
constexpr int Ln   = 131072;
constexpr int Cn   = 16;
constexpr int Lout = Ln - 1;
constexpr int CG   = Cn / 4;                     // f4 per position
constexpr int OPW  = 56;                         // outputs per wave
constexpr int NSPAN = (Lout + OPW - 1) / OPW;    // 2341
constexpr int WPB  = 4;                          // waves per 256-block
constexpr int XBLK = (NSPAN + WPB - 1) / WPB;    // 586

typedef float f4 __attribute__((ext_vector_type(4)));

__global__ __launch_bounds__(256)
void mop_kernel(const f4* __restrict__ x, f4* __restrict__ outp) {
    f4* dens = outp + (size_t)Bn * Lout * CG;

    const int lane = threadIdx.x & 63;
    const int span = blockIdx.x * WPB + (threadIdx.x >> 6);
    const int b    = blockIdx.y;
    if (span >= NSPAN) return;

    // input position this lane covers (window support for outputs l0..l0+55)
    const int p = span * OPW - 3 + lane;

    f4 v0 = (f4)0.f, v1 = (f4)0.f, v2 = (f4)0.f, v3 = (f4)0.f;
    if (p >= 0 && p < Ln) {
        const f4* xp = x + ((size_t)b * Ln + p) * CG;
        v0 = xp[0]; v1 = xp[1]; v2 = xp[2]; v3 = xp[3];
    }

    // nibble-packed one-hot indicator: value v in 1..4 -> nibble v gets 1;
    // v==0 contributes nothing. 2 channels per u32 word.
    float vals[16] = {v0.x, v0.y, v0.z, v0.w, v1.x, v1.y, v1.z, v1.w,
                      v2.x, v2.y, v2.z, v2.w, v3.x, v3.y, v3.z, v3.w};
    uint32_t E[8];
    #pragma unroll
    for (int i = 0; i < 8; ++i) {
        int a0 = (int)vals[2 * i], a1 = (int)vals[2 * i + 1];
        uint32_t n0 = (1u << (4 * a0)) >> 4;   // v=0 underflows to 0
        uint32_t n1 = (1u << (4 * a1)) >> 4;
        E[i] = n0 | (n1 << 16);
    }

    // 9-wide forward window sum A(k) = sum E(k..k+8), valid for k <= 55.
    // Nibble adds never carry (max 9 < 16).
    uint32_t A[8];
    #pragma unroll
    for (int i = 0; i < 8; ++i) {
        uint32_t e  = E[i];
        uint32_t b1 = e  + __shfl_down(e, 1);
        uint32_t b2 = b1 + __shfl_down(b1, 2);
        uint32_t b4 = b2 + __shfl_down(b2, 4);
        A[i] = b4 + __shfl_down(e, 8);
    }

    const int l = span * OPW + lane;           // output position of lane k
    if (lane < OPW && l < Lout) {
        float o[16], dd[16];
        #pragma unroll
        for (int i = 0; i < 8; ++i) {
            #pragma unroll
            for (int h = 0; h < 2; ++h) {
                uint32_t w = h ? (A[i] >> 16) : (A[i] & 0xFFFFu);
                int c1 = w & 15, c2 = (w >> 4) & 15, c3 = (w >> 8) & 15, c4 = (w >> 12) & 15;
                int m = max(max(c1, c2), max(c3, c4));
                // tie-averaged argmax (softmax@1e10 == 1/n per max bin)
                int n = (c1 == m) + (c2 == m) + (c3 == m) + (c4 == m);
                int s = (c1 == m) + 2 * (c2 == m) + 3 * (c3 == m) + 4 * (c4 == m);
                float r = (n == 1) ? 1.0f : (n == 2) ? 0.5f : (n == 3) ? (1.0f / 3.0f) : 0.25f;
                int c = 2 * i + h;
                o[c]  = (m == 0) ? 0.0f : (float)s * r;   // m==0 -> bin 0 wins alone
                dd[c] = (m == 0) ? 1.0f : (float)m;
            }
        }
        f4* ob = outp + ((size_t)b * Lout + l) * CG;
        f4* db = dens + ((size_t)b * Lout + l) * CG;
        #pragma unroll
        for (int q = 0; q < 4; ++q) {
            f4 o4 = {o[4 * q], o[4 * q + 1], o[4 * q + 2], o[4 * q + 3]};
            ob[q] = o4;   // plain store: L2 merges the 4x16B into full lines
        }
        #pragma unroll
        for (int q = 0; q < 4; ++q) {
            f4 d4 = {dd[4 * q], dd[4 * q + 1], dd[4 * q + 2], dd[4 * q + 3]};
            db[q] = d4;
        }
    }
}

extern "C" void kernel_launch(void* const* d_in, const int* in_sizes, int n_in,
                              void* d_out, int out_size, void* d_ws, size_t ws_size,
                              hipStream_t stream) {
    const f4* x = (const f4*)d_in[0];
    f4* outp = (f4*)d_out;
    dim3 grid(XBLK, Bn);
    mop_kernel<<<grid, 256, 0, stream>>>(x, outp);
}

// Round 8
// 187.883 us; speedup vs baseline: 1.3501x; 1.0649x over previous
//
#include <hip/hip_runtime.h>
#include <stdint.h>

// x: [B=8, L=131072, C=16] f32, integer values in [0,5). K=9, pad_l=3, pad_r=4
// -> output length L-1 = 131071. Outputs (soft-argmax, density) each
// [B, Lout, C] f32, concatenated flat in d_out.
//
// R8: every global memory instruction is a fully-contiguous 1KB wave access
// (the strided 16B-per-lane/64B-stride instructions of R2/R4/R7 all plateau
// at ~80us from address-request amplification; contiguous streams run at
// 6.7 TB/s). Three stages per block of 224 outputs:
//   1) contiguous load of 232 pos x 64B, pack float->u8 codes into LDS planes
//   2) per-wave R6 window tree (nibble one-hot, shfl_down 9-sum), stage
//      packed counts A (8 u32/pos) into LDS (12-word rows: 16B-aligned,
//      bank-balanced)
//   3) per-thread argmax epilogue, contiguous f4 stores for both arrays
constexpr int Bn   = 8;
constexpr int Ln   = 131072;
constexpr int Lout = Ln - 1;
constexpr int OPB  = 224;                    // outputs per block (4 waves x 56)
constexpr int IPB  = OPB + 8;                // 232 input positions
constexpr int NBLKX = (Lout + OPB - 1) / OPB;  // 586

typedef float f4 __attribute__((ext_vector_type(4)));

__global__ __launch_bounds__(256)
void mop_kernel(const f4* __restrict__ x, f4* __restrict__ outp) {
    __shared__ uint32_t sIn[4 * IPB];        // [quad][pos] u8x4 codes, 3.7KB
    __shared__ uint32_t sA[OPB * 12];        // per-pos 8 count-words, padded rows, 10.5KB
    f4* dens = outp + (size_t)Bn * Lout * 4;

    const int t  = threadIdx.x;
    const int b  = blockIdx.y;
    const int l0 = blockIdx.x * OPB;

    // ---- stage 1: contiguous global load + u8-code pack into LDS ----
    const f4* xb = x + ((size_t)b * Ln + l0 - 3) * 4;  // f4 slot 0 <-> (pos l0-3, q0)
    #pragma unroll
    for (int r = 0; r < 4; ++r) {
        int j = t + 256 * r;                 // f4 slot: pos = l0-3 + j/4, quad = j&3
        if (j < 4 * IPB) {
            int p = l0 - 3 + (j >> 2);
            f4 v = (f4)0.f;
            if (p >= 0 && p < Ln) v = xb[j];
            uint32_t code = ((uint32_t)(int)v.x)        | ((uint32_t)(int)v.y << 8)
                          | ((uint32_t)(int)v.z << 16)  | ((uint32_t)(int)v.w << 24);
            sIn[(j & 3) * IPB + (j >> 2)] = code;       // plane-major (conflict-free both ways)
        }
    }
    __syncthreads();

    // ---- stage 2: per-wave 9-window nibble tree, stage packed counts ----
    {
        const int lane = t & 63, w = t >> 6;
        const int P = 56 * w + lane;         // local input index this lane covers
        uint32_t cws[4];
        #pragma unroll
        for (int q = 0; q < 4; ++q) cws[q] = sIn[q * IPB + P];

        // nibble one-hot per channel (v in 1..4 -> nibble v; v==0 -> nothing),
        // 2 channels per u32 (counts <= 9 < 16: no carry).
        uint32_t E[8], A[8];
        #pragma unroll
        for (int q = 0; q < 4; ++q) {
            uint32_t cw = cws[q];
            int a0 = cw & 255, a1 = (cw >> 8) & 255, a2 = (cw >> 16) & 255, a3 = cw >> 24;
            E[2 * q]     = ((1u << (4 * a0)) >> 4) | (((1u << (4 * a1)) >> 4) << 16);
            E[2 * q + 1] = ((1u << (4 * a2)) >> 4) | (((1u << (4 * a3)) >> 4) << 16);
        }
        #pragma unroll
        for (int i = 0; i < 8; ++i) {        // A(k) = sum E(k..k+8), valid k<56
            uint32_t e  = E[i];
            uint32_t s1 = e  + __shfl_down(e, 1);
            uint32_t s2 = s1 + __shfl_down(s1, 2);
            uint32_t s4 = s2 + __shfl_down(s2, 4);
            A[i] = s4 + __shfl_down(e, 8);
        }
        if (lane < 56) {
            uint32_t* row = &sA[P * 12];     // 48B rows: 16B-aligned, banks spread
            #pragma unroll
            for (int i = 0; i < 8; ++i) row[i] = A[i];
        }
    }
    __syncthreads();

    // ---- stage 3: argmax epilogue + fully-contiguous stores ----
    const int nf4 = 4 * min(OPB, Lout - l0);
    f4* ob = outp + ((size_t)b * Lout + l0) * 4;
    f4* db = dens + ((size_t)b * Lout + l0) * 4;
    #pragma unroll
    for (int r = 0; r < 4; ++r) {
        int j = t + 256 * r;                 // f4 slot: pos p=j>>2, quad q=j&3
        if (j < nf4) {
            int p = j >> 2, q = j & 3;
            uint32_t w0 = sA[p * 12 + 2 * q], w1 = sA[p * 12 + 2 * q + 1];
            uint32_t ws[4] = {w0 & 0xFFFFu, w0 >> 16, w1 & 0xFFFFu, w1 >> 16};
            float o[4], d[4];
            #pragma unroll
            for (int c = 0; c < 4; ++c) {
                uint32_t wv = ws[c];
                int c1 = wv & 15, c2 = (wv >> 4) & 15, c3 = (wv >> 8) & 15, c4 = (wv >> 12) & 15;
                int m = max(max(c1, c2), max(c3, c4));
                // tie-averaged argmax (softmax@1e10 == 1/n per max bin)
                int n = (c1 == m) + (c2 == m) + (c3 == m) + (c4 == m);
                int s = (c1 == m) + 2 * (c2 == m) + 3 * (c3 == m) + 4 * (c4 == m);
                float rr = (n == 1) ? 1.0f : (n == 2) ? 0.5f : (n == 3) ? (1.0f / 3.0f) : 0.25f;
                o[c] = (m == 0) ? 0.0f : (float)s * rr;  // m==0 -> bin 0 wins alone
                d[c] = (m == 0) ? 1.0f : (float)m;
            }
            f4 o4 = {o[0], o[1], o[2], o[3]};
            f4 d4 = {d[0], d[1], d[2], d[3]};
            ob[j] = o4;                      // 64 lanes x 16B contiguous = 1KB/instr
            db[j] = d4;
        }
    }
}

extern "C" void kernel_launch(void* const* d_in, const int* in_sizes, int n_in,
                              void* d_out, int out_size, void* d_ws, size_t ws_size,
                              hipStream_t stream) {
    const f4* x = (const f4*)d_in[0];
    f4* outp = (f4*)d_out;
    dim3 grid(NBLKX, Bn);
    mop_kernel<<<grid, 256, 0, stream>>>(x, outp);
}

// Round 9
// 186.927 us; speedup vs baseline: 1.3570x; 1.0051x over previous
//
#include <hip/hip_runtime.h>
#include <stdint.h>

// x: [B=8, L=131072, C=16] f32, integer values in [0,5). K=9, pad_l=3, pad_r=4
// -> output length L-1 = 131071. Outputs (soft-argmax, density) each
// [B, Lout, C] f32, concatenated flat in d_out.
//
// R9 = R8 (all global instructions fully contiguous 1KB/wave; LDS staging;
// nibble-packed window counts via shfl_down tree) + NONTEMPORAL epilogue
// stores. Stores are now full-sector contiguous (unlike R6's 16B-per-64B
// pattern that made NT amplify writes 1.94x), so NT streams at fill rate
// (6.7 TB/s measured) and keeps L2/L3 free for the resident input.
constexpr int Bn   = 8;
constexpr int Ln   = 131072;
constexpr int Lout = Ln - 1;
constexpr int OPB  = 224;                    // outputs per block (4 waves x 56)
constexpr int IPB  = OPB + 8;                // 232 input positions
constexpr int NBLKX = (Lout + OPB - 1) / OPB;  // 586

typedef float f4 __attribute__((ext_vector_type(4)));

__global__ __launch_bounds__(256)
void mop_kernel(const f4* __restrict__ x, f4* __restrict__ outp) {
    __shared__ uint32_t sIn[4 * IPB];        // [quad][pos] u8x4 codes, 3.7KB
    __shared__ uint32_t sA[OPB * 12];        // per-pos 8 count-words, padded rows, 10.5KB
    f4* dens = outp + (size_t)Bn * Lout * 4;

    const int t  = threadIdx.x;
    const int b  = blockIdx.y;
    const int l0 = blockIdx.x * OPB;

    // ---- stage 1: contiguous global load + u8-code pack into LDS ----
    const f4* xb = x + ((size_t)b * Ln + l0 - 3) * 4;  // f4 slot 0 <-> (pos l0-3, q0)
    #pragma unroll
    for (int r = 0; r < 4; ++r) {
        int j = t + 256 * r;                 // f4 slot: pos = l0-3 + j/4, quad = j&3
        if (j < 4 * IPB) {
            int p = l0 - 3 + (j >> 2);
            f4 v = (f4)0.f;
            if (p >= 0 && p < Ln) v = xb[j];
            uint32_t code = ((uint32_t)(int)v.x)        | ((uint32_t)(int)v.y << 8)
                          | ((uint32_t)(int)v.z << 16)  | ((uint32_t)(int)v.w << 24);
            sIn[(j & 3) * IPB + (j >> 2)] = code;       // plane-major (conflict-free both ways)
        }
    }
    __syncthreads();

    // ---- stage 2: per-wave 9-window nibble tree, stage packed counts ----
    {
        const int lane = t & 63, w = t >> 6;
        const int P = 56 * w + lane;         // local input index this lane covers
        uint32_t cws[4];
        #pragma unroll
        for (int q = 0; q < 4; ++q) cws[q] = sIn[q * IPB + P];

        // nibble one-hot per channel (v in 1..4 -> nibble v; v==0 -> nothing),
        // 2 channels per u32 (counts <= 9 < 16: no carry).
        uint32_t E[8], A[8];
        #pragma unroll
        for (int q = 0; q < 4; ++q) {
            uint32_t cw = cws[q];
            int a0 = cw & 255, a1 = (cw >> 8) & 255, a2 = (cw >> 16) & 255, a3 = cw >> 24;
            E[2 * q]     = ((1u << (4 * a0)) >> 4) | (((1u << (4 * a1)) >> 4) << 16);
            E[2 * q + 1] = ((1u << (4 * a2)) >> 4) | (((1u << (4 * a3)) >> 4) << 16);
        }
        #pragma unroll
        for (int i = 0; i < 8; ++i) {        // A(k) = sum E(k..k+8), valid k<56
            uint32_t e  = E[i];
            uint32_t s1 = e  + __shfl_down(e, 1);
            uint32_t s2 = s1 + __shfl_down(s1, 2);
            uint32_t s4 = s2 + __shfl_down(s2, 4);
            A[i] = s4 + __shfl_down(e, 8);
        }
        if (lane < 56) {
            uint32_t* row = &sA[P * 12];     // 48B rows: 16B-aligned, banks spread
            #pragma unroll
            for (int i = 0; i < 8; ++i) row[i] = A[i];
        }
    }
    __syncthreads();

    // ---- stage 3: argmax epilogue + fully-contiguous NT stores ----
    const int nf4 = 4 * min(OPB, Lout - l0);
    f4* ob = outp + ((size_t)b * Lout + l0) * 4;
    f4* db = dens + ((size_t)b * Lout + l0) * 4;
    #pragma unroll
    for (int r = 0; r < 4; ++r) {
        int j = t + 256 * r;                 // f4 slot: pos p=j>>2, quad q=j&3
        if (j < nf4) {
            int p = j >> 2, q = j & 3;
            uint32_t w0 = sA[p * 12 + 2 * q], w1 = sA[p * 12 + 2 * q + 1];
            uint32_t ws[4] = {w0 & 0xFFFFu, w0 >> 16, w1 & 0xFFFFu, w1 >> 16};
            float o[4], d[4];
            #pragma unroll
            for (int c = 0; c < 4; ++c) {
                uint32_t wv = ws[c];
                int c1 = wv & 15, c2 = (wv >> 4) & 15, c3 = (wv >> 8) & 15, c4 = (wv >> 12) & 15;
                int m = max(max(c1, c2), max(c3, c4));
                // tie-averaged argmax (softmax@1e10 == 1/n per max bin)
                int n = (c1 == m) + (c2 == m) + (c3 == m) + (c4 == m);
                int s = (c1 == m) + 2 * (c2 == m) + 3 * (c3 == m) + 4 * (c4 == m);
                float rr = (n == 1) ? 1.0f : (n == 2) ? 0.5f : (n == 3) ? (1.0f / 3.0f) : 0.25f;
                o[c] = (m == 0) ? 0.0f : (float)s * rr;  // m==0 -> bin 0 wins alone
                d[c] = (m == 0) ? 1.0f : (float)m;
            }
            f4 o4 = {o[0], o[1], o[2], o[3]};
            f4 d4 = {d[0], d[1], d[2], d[3]};
            __builtin_nontemporal_store(o4, &ob[j]);  // 1KB contiguous/wave: full sectors
            __builtin_nontemporal_store(d4, &db[j]);
        }
    }
}

extern "C" void kernel_launch(void* const* d_in, const int* in_sizes, int n_in,
                              void* d_out, int out_size, void* d_ws, size_t ws_size,
                              hipStream_t stream) {
    const f4* x = (const f4*)d_in[0];
    f4* outp = (f4*)d_out;
    dim3 grid(NBLKX, Bn);
    mop_kernel<<<grid, 256, 0, stream>>>(x, outp);
}